// Round 6
// baseline (2163.337 us; speedup 1.0000x reference)
//
#include <hip/hip_runtime.h>
#include <hip/hip_bf16.h>

#define THREADS 256

typedef _Float16 f16;
typedef f16 f16x8 __attribute__((ext_vector_type(8)));
typedef f16 f16x4 __attribute__((ext_vector_type(4)));

// ---------------- preprocessing ----------------

__global__ void count_deg_kernel(const int* __restrict__ col, int* __restrict__ deg, int E) {
    int e = blockIdx.x * blockDim.x + threadIdx.x;
    if (e < E) atomicAdd(&deg[col[e]], 1);
}

__global__ void dinv_kernel(const int* __restrict__ deg, float* __restrict__ dinv, int N) {
    int n = blockIdx.x * blockDim.x + threadIdx.x;
    if (n < N) {
        float d = (float)(deg[n] + 1);   // +1 self loop
        dinv[n] = 1.0f / sqrtf(d);
    }
}

// histogram of (descending) degree bins
__global__ void hist_deg_kernel(const int* __restrict__ deg, int* __restrict__ hist, int N) {
    int n = blockIdx.x * blockDim.x + threadIdx.x;
    if (n < N) {
        int b = 127 - min(deg[n], 127);   // descending: heavy nodes first
        atomicAdd(&hist[b], 1);
    }
}

// exclusive scan of 128 bins, one block
__global__ void scan_hist_kernel(const int* __restrict__ hist, int* __restrict__ binoff) {
    __shared__ int s[128];
    int t = threadIdx.x;
    int v = hist[t];
    s[t] = v;
    __syncthreads();
    for (int off = 1; off < 128; off <<= 1) {
        int x = (t >= off) ? s[t - off] : 0;
        __syncthreads();
        s[t] += x;
        __syncthreads();
    }
    binoff[t] = s[t] - v;
}

// order[] = node ids sorted by descending degree (counting sort)
__global__ void order_kernel(const int* __restrict__ deg, const int* __restrict__ binoff,
                             int* __restrict__ binfill, int* __restrict__ order, int N) {
    int n = blockIdx.x * blockDim.x + threadIdx.x;
    if (n < N) {
        int b = 127 - min(deg[n], 127);
        int p = binoff[b] + atomicAdd(&binfill[b], 1);
        order[p] = n;
    }
}

// scans over PADDED degree pdeg = (deg+7)&~7
__global__ void scanA_kernel(const int* __restrict__ deg, int* __restrict__ blocksum, int N) {
    __shared__ int s[THREADS];
    int t = threadIdx.x;
    int idx = blockIdx.x * THREADS + t;
    s[t] = (idx < N) ? ((deg[idx] + 7) & ~7) : 0;
    __syncthreads();
    for (int off = THREADS / 2; off > 0; off >>= 1) {
        if (t < off) s[t] += s[t + off];
        __syncthreads();
    }
    if (t == 0) blocksum[blockIdx.x] = s[0];
}

__global__ void scanB_kernel(const int* __restrict__ blocksum, int* __restrict__ blockoff, int NB) {
    __shared__ int s[512];
    int t = threadIdx.x;
    int v = (t < NB) ? blocksum[t] : 0;
    s[t] = v;
    __syncthreads();
    for (int off = 1; off < 512; off <<= 1) {
        int x = (t >= off) ? s[t - off] : 0;
        __syncthreads();
        s[t] += x;
        __syncthreads();
    }
    if (t < NB) blockoff[t] = s[t] - v;  // exclusive
}

__global__ void scanC_kernel(const int* __restrict__ deg, const int* __restrict__ blockoff,
                             int* __restrict__ rowptr, int N) {
    __shared__ int s[THREADS];
    int t = threadIdx.x;
    int idx = blockIdx.x * THREADS + t;
    int v = (idx < N) ? ((deg[idx] + 7) & ~7) : 0;
    s[t] = v;
    __syncthreads();
    for (int off = 1; off < THREADS; off <<= 1) {
        int x = (t >= off) ? s[t - off] : 0;
        __syncthreads();
        s[t] += x;
        __syncthreads();
    }
    int base = blockoff[blockIdx.x];
    if (idx < N) {
        rowptr[idx] = base + s[t] - v;       // exclusive prefix of padded degrees
        if (idx == N - 1) rowptr[N] = base + s[t];
    }
}

// fill padding slots with dummy node N (zero row)
__global__ void init_srcs_kernel(int* __restrict__ srcs, int total, int N) {
    int i = blockIdx.x * blockDim.x + threadIdx.x;
    if (i < total) srcs[i] = N;
}

// scatter edges into padded CSR (sorted by destination); 1 edge/thread
__global__ void fill_csr_kernel(const int* __restrict__ row, const int* __restrict__ col,
                                const int* __restrict__ rowptr, int* __restrict__ fill,
                                int* __restrict__ srcs, int E) {
    int e = blockIdx.x * blockDim.x + threadIdx.x;
    if (e < E) {
        int s = row[e], d = col[e];
        int p = rowptr[d] + atomicAdd(&fill[d], 1);
        srcs[p] = s;
    }
}

// zero the dummy feature row (node N) in both fp16 buffers
__global__ void zrow_kernel(f16* __restrict__ gA, f16* __restrict__ gB, int N) {
    int t = threadIdx.x;   // 32 threads
    gA[(size_t)N * 32 + t] = (f16)0.f;
    gB[(size_t)N * 32 + t] = (f16)0.f;
}

// ---------------- dense layers ----------------

// g16 = (f16)(dinv * (x @ W0 + b0))   — 8 lanes/node, 4 ch each
__global__ __launch_bounds__(256) void lin0_kernel(const float* __restrict__ x,
        const float* __restrict__ W0, const float* __restrict__ b0,
        const float* __restrict__ dinv, f16* __restrict__ g, int N) {
    __shared__ float Ws[128 * 32];
    int t = threadIdx.x;
    for (int i = t; i < 128 * 32; i += 256) Ws[i] = W0[i];
    __syncthreads();
    int node = blockIdx.x * 32 + (t >> 3);
    int lane = t & 7;
    if (node >= N) return;
    float4 o = ((const float4*)b0)[lane];
    const float* xr = x + (size_t)node * 128;
    for (int k = 0; k < 128; ++k) {
        float a = xr[k];
        float4 w = *(const float4*)&Ws[k * 32 + lane * 4];
        o.x += a * w.x; o.y += a * w.y; o.z += a * w.z; o.w += a * w.w;
    }
    float di = dinv[node];
    f16x4 st;
    st.x = (f16)(o.x * di); st.y = (f16)(o.y * di);
    st.z = (f16)(o.z * di); st.w = (f16)(o.w * di);
    ((f16x4*)g)[(size_t)node * 8 + lane] = st;
}

// SG layer on fp16 pre-scaled features, degree-sorted node order, padded CSR.
// 4 lanes/node, 64 nodes/block; inner loop always multiples of 8 edges.
__global__ __launch_bounds__(256) void sg_layer_kernel(const f16* __restrict__ g_in,
        f16* __restrict__ g_out16, float* __restrict__ h_out32,
        const int* __restrict__ rowptr, const int* __restrict__ srcs,
        const int* __restrict__ order, const float* __restrict__ dinv,
        const float* __restrict__ W, const float* __restrict__ b,
        int N, float bscale, int last) {
    __shared__ float Ws[32 * 32];
    __shared__ float agg[64][33];
    int t = threadIdx.x;
    for (int i = t; i < 32 * 32; i += 256) Ws[i] = W[i];
    int idx = blockIdx.x * 64 + (t >> 2);
    int node = (idx < N) ? order[idx] : -1;
    int lane = t & 3;
    int ln = t >> 2;
    float o0=0.f,o1=0.f,o2=0.f,o3=0.f,o4=0.f,o5=0.f,o6=0.f,o7=0.f;
    if (node >= 0) {
        const f16x8* g8 = (const f16x8*)g_in;
        f16x8 sv = g8[(size_t)node * 4 + lane];      // self-loop term
        o0=(float)sv[0]; o1=(float)sv[1]; o2=(float)sv[2]; o3=(float)sv[3];
        o4=(float)sv[4]; o5=(float)sv[5]; o6=(float)sv[6]; o7=(float)sv[7];
        int e = rowptr[node], e1 = rowptr[node + 1];
        for (; e < e1; e += 8) {
            int4 ia = *(const int4*)&srcs[e];        // 32B-aligned (padded CSR)
            int4 ib = *(const int4*)&srcs[e + 4];
            f16x8 v0 = g8[(size_t)ia.x * 4 + lane];
            f16x8 v1 = g8[(size_t)ia.y * 4 + lane];
            f16x8 v2 = g8[(size_t)ia.z * 4 + lane];
            f16x8 v3 = g8[(size_t)ia.w * 4 + lane];
            f16x8 v4 = g8[(size_t)ib.x * 4 + lane];
            f16x8 v5 = g8[(size_t)ib.y * 4 + lane];
            f16x8 v6 = g8[(size_t)ib.z * 4 + lane];
            f16x8 v7 = g8[(size_t)ib.w * 4 + lane];
            o0 = fmaf((float)v0[0], 1.0f, o0); o0 = fmaf((float)v1[0], 1.0f, o0);
            o0 = fmaf((float)v2[0], 1.0f, o0); o0 = fmaf((float)v3[0], 1.0f, o0);
            o0 = fmaf((float)v4[0], 1.0f, o0); o0 = fmaf((float)v5[0], 1.0f, o0);
            o0 = fmaf((float)v6[0], 1.0f, o0); o0 = fmaf((float)v7[0], 1.0f, o0);
            o1 = fmaf((float)v0[1], 1.0f, o1); o1 = fmaf((float)v1[1], 1.0f, o1);
            o1 = fmaf((float)v2[1], 1.0f, o1); o1 = fmaf((float)v3[1], 1.0f, o1);
            o1 = fmaf((float)v4[1], 1.0f, o1); o1 = fmaf((float)v5[1], 1.0f, o1);
            o1 = fmaf((float)v6[1], 1.0f, o1); o1 = fmaf((float)v7[1], 1.0f, o1);
            o2 = fmaf((float)v0[2], 1.0f, o2); o2 = fmaf((float)v1[2], 1.0f, o2);
            o2 = fmaf((float)v2[2], 1.0f, o2); o2 = fmaf((float)v3[2], 1.0f, o2);
            o2 = fmaf((float)v4[2], 1.0f, o2); o2 = fmaf((float)v5[2], 1.0f, o2);
            o2 = fmaf((float)v6[2], 1.0f, o2); o2 = fmaf((float)v7[2], 1.0f, o2);
            o3 = fmaf((float)v0[3], 1.0f, o3); o3 = fmaf((float)v1[3], 1.0f, o3);
            o3 = fmaf((float)v2[3], 1.0f, o3); o3 = fmaf((float)v3[3], 1.0f, o3);
            o3 = fmaf((float)v4[3], 1.0f, o3); o3 = fmaf((float)v5[3], 1.0f, o3);
            o3 = fmaf((float)v6[3], 1.0f, o3); o3 = fmaf((float)v7[3], 1.0f, o3);
            o4 = fmaf((float)v0[4], 1.0f, o4); o4 = fmaf((float)v1[4], 1.0f, o4);
            o4 = fmaf((float)v2[4], 1.0f, o4); o4 = fmaf((float)v3[4], 1.0f, o4);
            o4 = fmaf((float)v4[4], 1.0f, o4); o4 = fmaf((float)v5[4], 1.0f, o4);
            o4 = fmaf((float)v6[4], 1.0f, o4); o4 = fmaf((float)v7[4], 1.0f, o4);
            o5 = fmaf((float)v0[5], 1.0f, o5); o5 = fmaf((float)v1[5], 1.0f, o5);
            o5 = fmaf((float)v2[5], 1.0f, o5); o5 = fmaf((float)v3[5], 1.0f, o5);
            o5 = fmaf((float)v4[5], 1.0f, o5); o5 = fmaf((float)v5[5], 1.0f, o5);
            o5 = fmaf((float)v6[5], 1.0f, o5); o5 = fmaf((float)v7[5], 1.0f, o5);
            o6 = fmaf((float)v0[6], 1.0f, o6); o6 = fmaf((float)v1[6], 1.0f, o6);
            o6 = fmaf((float)v2[6], 1.0f, o6); o6 = fmaf((float)v3[6], 1.0f, o6);
            o6 = fmaf((float)v4[6], 1.0f, o6); o6 = fmaf((float)v5[6], 1.0f, o6);
            o6 = fmaf((float)v6[6], 1.0f, o6); o6 = fmaf((float)v7[6], 1.0f, o6);
            o7 = fmaf((float)v0[7], 1.0f, o7); o7 = fmaf((float)v1[7], 1.0f, o7);
            o7 = fmaf((float)v2[7], 1.0f, o7); o7 = fmaf((float)v3[7], 1.0f, o7);
            o7 = fmaf((float)v4[7], 1.0f, o7); o7 = fmaf((float)v5[7], 1.0f, o7);
            o7 = fmaf((float)v6[7], 1.0f, o7); o7 = fmaf((float)v7[7], 1.0f, o7);
        }
    }
    int c = lane * 8;
    agg[ln][c + 0] = o0; agg[ln][c + 1] = o1; agg[ln][c + 2] = o2; agg[ln][c + 3] = o3;
    agg[ln][c + 4] = o4; agg[ln][c + 5] = o5; agg[ln][c + 6] = o6; agg[ln][c + 7] = o7;
    __syncthreads();
    if (node >= 0) {
        float4 ma = make_float4(0.f, 0.f, 0.f, 0.f);
        float4 mb = make_float4(0.f, 0.f, 0.f, 0.f);
        for (int k = 0; k < 32; ++k) {
            float a = agg[ln][k];
            float4 wa = *(const float4*)&Ws[k * 32 + c];
            float4 wb = *(const float4*)&Ws[k * 32 + c + 4];
            ma.x += a * wa.x; ma.y += a * wa.y; ma.z += a * wa.z; ma.w += a * wa.w;
            mb.x += a * wb.x; mb.y += a * wb.y; mb.z += a * wb.z; mb.w += a * wb.w;
        }
        float di = dinv[node];
        float4 ba = *(const float4*)&b[c];
        float4 bb = *(const float4*)&b[c + 4];
        float r0 = fmaxf(fmaf(di, ma.x, bscale * ba.x), 0.f);
        float r1 = fmaxf(fmaf(di, ma.y, bscale * ba.y), 0.f);
        float r2 = fmaxf(fmaf(di, ma.z, bscale * ba.z), 0.f);
        float r3 = fmaxf(fmaf(di, ma.w, bscale * ba.w), 0.f);
        float r4 = fmaxf(fmaf(di, mb.x, bscale * bb.x), 0.f);
        float r5 = fmaxf(fmaf(di, mb.y, bscale * bb.y), 0.f);
        float r6 = fmaxf(fmaf(di, mb.z, bscale * bb.z), 0.f);
        float r7 = fmaxf(fmaf(di, mb.w, bscale * bb.w), 0.f);
        if (!last) {
            float sc = 2.0f * di;                     // s_{l+1} = 2 s_l
            f16x8 st;
            st[0]=(f16)(r0*sc); st[1]=(f16)(r1*sc); st[2]=(f16)(r2*sc); st[3]=(f16)(r3*sc);
            st[4]=(f16)(r4*sc); st[5]=(f16)(r5*sc); st[6]=(f16)(r6*sc); st[7]=(f16)(r7*sc);
            ((f16x8*)g_out16)[(size_t)node * 4 + lane] = st;
        } else {
            const float inv = 1.0f / 1073741824.0f;   // 2^-30
            float4 wa = make_float4(r0*inv, r1*inv, r2*inv, r3*inv);
            float4 wb = make_float4(r4*inv, r5*inv, r6*inv, r7*inv);
            float4* hp = (float4*)(h_out32 + (size_t)node * 32 + c);
            hp[0] = wa; hp[1] = wb;
        }
    }
}

// out = h @ W32 + b32  (h: [N,32] fp32, W32: [32,64]) — 16 lanes/node
__global__ __launch_bounds__(256) void linout_kernel(const float* __restrict__ h,
        const float* __restrict__ W32, const float* __restrict__ b32,
        float* __restrict__ out, int N) {
    __shared__ float Ws[32 * 64];
    int t = threadIdx.x;
    for (int i = t; i < 32 * 64; i += 256) Ws[i] = W32[i];
    __syncthreads();
    int node = blockIdx.x * 16 + (t >> 4);
    int lane = t & 15;
    if (node >= N) return;
    float4 o = ((const float4*)b32)[lane];
    const float* hr = h + (size_t)node * 32;
    for (int k = 0; k < 32; ++k) {
        float a = hr[k];
        float4 w = *(const float4*)&Ws[k * 64 + lane * 4];
        o.x += a * w.x; o.y += a * w.y; o.z += a * w.z; o.w += a * w.w;
    }
    ((float4*)out)[(size_t)node * 16 + lane] = o;
}

// ---------------- launch ----------------

extern "C" void kernel_launch(void* const* d_in, const int* in_sizes, int n_in,
                              void* d_out, int out_size, void* d_ws, size_t ws_size,
                              hipStream_t stream) {
    const float* x     = (const float*)d_in[0];
    const float* W0    = (const float*)d_in[1];
    const float* b0    = (const float*)d_in[2];
    const float* Wsall = (const float*)d_in[3];
    const float* bsall = (const float*)d_in[4];
    const float* W32   = (const float*)d_in[5];
    const float* b32   = (const float*)d_in[6];
    const int*   ei    = (const int*)d_in[7];

    const int N   = in_sizes[0] / 128;
    const int E   = in_sizes[7] / 2;
    const int NSG = in_sizes[3] / (32 * 32);
    const int* erow = ei;       // sources
    const int* ecol = ei + E;   // destinations
    const int PADTOT = E + 8 * N + 8;   // upper bound on padded CSR size

    char* ws = (char*)d_ws;
    size_t off = 0;
    auto alloc = [&](size_t bytes) { size_t p = off; off += (bytes + 255) & ~(size_t)255; return p; };
    size_t degOff   = alloc((size_t)N * 4);      // -- zeroed region start
    size_t fillOff  = alloc((size_t)N * 4);
    size_t histOff  = alloc(128 * 4);
    size_t bfilOff  = alloc(128 * 4);            // -- zeroed region end
    size_t rpOff    = alloc((size_t)(N + 1) * 4);
    size_t bsumOff  = alloc(512 * 4);
    size_t boffOff  = alloc(512 * 4);
    size_t binoOff  = alloc(128 * 4);
    size_t dinvOff  = alloc((size_t)N * 4);
    size_t ordOff   = alloc((size_t)N * 4);
    size_t srcsOff  = alloc((size_t)PADTOT * 4);
    size_t gAOff    = alloc((size_t)(N + 1) * 32 * 2);   // fp16 features (+dummy row)
    size_t gBOff    = alloc((size_t)(N + 1) * 32 * 2);
    size_t hFOff    = alloc((size_t)N * 32 * 4);

    int*   deg    = (int*)(ws + degOff);
    int*   fill   = (int*)(ws + fillOff);
    int*   hist   = (int*)(ws + histOff);
    int*   bfil   = (int*)(ws + bfilOff);
    int*   rowptr = (int*)(ws + rpOff);
    int*   bsum   = (int*)(ws + bsumOff);
    int*   boff   = (int*)(ws + boffOff);
    int*   bino   = (int*)(ws + binoOff);
    float* dinv   = (float*)(ws + dinvOff);
    int*   order  = (int*)(ws + ordOff);
    int*   srcs   = (int*)(ws + srcsOff);
    f16*   gA     = (f16*)(ws + gAOff);
    f16*   gB     = (f16*)(ws + gBOff);
    float* hF     = (float*)(ws + hFOff);

    // zero deg + fill + hist + binfill (contiguous)
    hipMemsetAsync(ws + degOff, 0, bfilOff + 128 * 4 - degOff, stream);

    const int egrid = (E + THREADS - 1) / THREADS;
    const int ngrid = (N + THREADS - 1) / THREADS;
    const int pgrid = (PADTOT + THREADS - 1) / THREADS;

    count_deg_kernel<<<egrid, THREADS, 0, stream>>>(ecol, deg, E);
    dinv_kernel<<<ngrid, THREADS, 0, stream>>>(deg, dinv, N);
    hist_deg_kernel<<<ngrid, THREADS, 0, stream>>>(deg, hist, N);
    scan_hist_kernel<<<1, 128, 0, stream>>>(hist, bino);
    order_kernel<<<ngrid, THREADS, 0, stream>>>(deg, bino, bfil, order, N);
    scanA_kernel<<<ngrid, THREADS, 0, stream>>>(deg, bsum, N);
    scanB_kernel<<<1, 512, 0, stream>>>(bsum, boff, ngrid);
    scanC_kernel<<<ngrid, THREADS, 0, stream>>>(deg, boff, rowptr, N);
    init_srcs_kernel<<<pgrid, THREADS, 0, stream>>>(srcs, PADTOT, N);
    fill_csr_kernel<<<egrid, THREADS, 0, stream>>>(erow, ecol, rowptr, fill, srcs, E);
    zrow_kernel<<<1, 32, 0, stream>>>(gA, gB, N);

    lin0_kernel<<<(N + 31) / 32, 256, 0, stream>>>(x, W0, b0, dinv, gA, N);

    f16* cur = gA;
    f16* nxt = gB;
    for (int l = 0; l < NSG; ++l) {
        int last = (l == NSG - 1) ? 1 : 0;
        float bscale = (float)(1u << l);             // s_l = 2^l
        sg_layer_kernel<<<(N + 63) / 64, 256, 0, stream>>>(
            cur, nxt, hF, rowptr, srcs, order, dinv,
            Wsall + (size_t)l * 32 * 32, bsall + (size_t)l * 32, N, bscale, last);
        f16* tmp = cur; cur = nxt; nxt = tmp;
    }

    linout_kernel<<<(N + 15) / 16, 256, 0, stream>>>(hF, W32, b32, (float*)d_out, N);
}